// Round 5
// baseline (510.252 us; speedup 1.0000x reference)
//
#include <hip/hip_runtime.h>

// RGCN 2-layer, basis decomposition, mean aggregation - MFMA, latency-optimized.
// N=50000, E=1.6M, R=8, feat 128->128->64.
//
// Round-5 structure: fused layer kernel keeps ONLY meanT in LDS (8.7 KB);
// B-fragments (W_r^T) are read directly from global (L2-resident, 432 KB).
// Gather processes both 16-node passes concurrently (8 row-loads in flight
// per 16-lane group) and prefetches cnt/ell one relation ahead.

#define N_NODES 50000
#define N_EDGES 1600000
#define N_REL   8
#define CAP     32

typedef __attribute__((ext_vector_type(8))) short short8;
typedef __attribute__((ext_vector_type(4))) float f32x4;

__device__ __forceinline__ ushort f2bf(float x) {
    unsigned u = __builtin_bit_cast(unsigned, x);
    u += 0x7FFFu + ((u >> 16) & 1u);   // RNE
    return (ushort)(u >> 16);
}
__device__ __forceinline__ float u2f(unsigned u) {
    return __builtin_bit_cast(float, u);
}

__global__ void zero_i32_kernel(int* __restrict__ p, int n) {
    int i = blockIdx.x * 256 + threadIdx.x;
    if (i < n) p[i] = 0;
}

// x (N,128) f32 -> xbf ((N+1),128) bf16, row N zeroed (gather sentinel).
__global__ void to_bf16_kernel(const float* __restrict__ in,
                               ushort* __restrict__ out) {
    int i = blockIdx.x * 256 + threadIdx.x;
    int total = (N_NODES + 1) * 16;
    if (i >= total) return;
    int base = i * 8;
    short8 v;
    if (base < N_NODES * 128) {
        f32x4 a = *(const f32x4*)(in + base);
        f32x4 b = *(const f32x4*)(in + base + 4);
        v = (short8){(short)f2bf(a.x), (short)f2bf(a.y), (short)f2bf(a.z),
                     (short)f2bf(a.w), (short)f2bf(b.x), (short)f2bf(b.y),
                     (short)f2bf(b.z), (short)f2bf(b.w)};
    } else {
        v = (short8){0, 0, 0, 0, 0, 0, 0, 0};
    }
    *(short8*)(out + base) = v;
}

// Wt[(r*outc + n)*128 + k] = bf16( sum_b comp[r,b]*basis[b,k,n] ), r==8 -> root
__global__ void compose_wt_kernel(const float* __restrict__ basis,
                                  const float* __restrict__ comp,
                                  const float* __restrict__ root,
                                  ushort* __restrict__ Wt,
                                  int outc, int total) {
    int i = blockIdx.x * 256 + threadIdx.x;
    if (i >= total) return;
    int per_r = outc << 7;
    int r = i / per_r;
    int rem = i - r * per_r;
    int n = rem >> 7;
    int k = rem & 127;
    float s;
    if (r == N_REL) {
        s = root[k * outc + n];
    } else {
        s = 0.f;
#pragma unroll
        for (int b = 0; b < 4; ++b)
            s += comp[r * 4 + b] * basis[(b * 128 + k) * outc + n];
    }
    Wt[i] = f2bf(s);
}

__global__ void build_ell_kernel(const int* __restrict__ A,
                                 const int* __restrict__ etype,
                                 int* __restrict__ cnt,
                                 int* __restrict__ ell) {
    int e = blockIdx.x * 256 + threadIdx.x;
    if (e >= N_EDGES) return;
    int s = A[e];
    int d = A[N_EDGES + e];
    int t = etype[e];
    int seg = t * N_NODES + d;
    int slot = atomicAdd(&cnt[seg], 1);
    if (slot < CAP) ell[(size_t)seg * CAP + slot] = s;
}

template <int OUTC, bool RELU, bool BF16OUT>
__global__ __launch_bounds__(256, 4)
void rgcn_layer_mfma(const ushort* __restrict__ xbf,  // (N+1,128) bf16
                     const int* __restrict__ cnt,     // (R*N,)
                     const int* __restrict__ ell,     // (R*N,CAP)
                     const ushort* __restrict__ Wt,   // (R+1,OUTC,128) bf16
                     const float* __restrict__ bias,  // (OUTC,)
                     void* __restrict__ outp) {       // (N,OUTC)
    constexpr int LDK = 136;        // padded k-stride (272 B rows)
    constexpr int TN  = 32;
    constexpr int NTW = OUTC / 32;

    __shared__ ushort meanT[TN * LDK];   // 8.7 KB — the ONLY LDS

    const int tid   = threadIdx.x;
    const int lane  = tid & 63;
    const int wave  = tid >> 6;
    const int nbase = blockIdx.x * TN;

    // gather mapping: 16 lanes per node-pair, lane j owns features [8j,8j+8)
    const int g  = tid >> 4;
    const int j  = tid & 15;
    const int j8 = j * 8;
    const int gb = lane & 48;

    // MFMA mapping
    const int rt = wave & 1;
    const int ch = wave >> 1;
    const int lr = lane & 15;
    const int kc = (lane >> 4) * 8;

    const int gn0 = nbase + g;        // pass-0 node
    const int gn1 = nbase + 16 + g;   // pass-1 node
    const bool v0 = gn0 < N_NODES;
    const bool v1 = gn1 < N_NODES;
    const int sg0 = v0 ? gn0 : 0;     // clamped for safe addressing
    const int sg1 = v1 ? gn1 : 0;

    f32x4 acc[NTW];
#pragma unroll
    for (int t = 0; t < NTW; ++t) acc[t] = (f32x4){0.f, 0.f, 0.f, 0.f};

    // ---- prefetch r=0 cnt/ell ----
    int c0 = v0 ? cnt[sg0] : 0;
    int c1 = v1 ? cnt[sg1] : 0;
    int pA0 = ell[(size_t)sg0 * CAP + j];
    int pB0 = ell[(size_t)sg0 * CAP + 16 + j];
    int pA1 = ell[(size_t)sg1 * CAP + j];
    int pB1 = ell[(size_t)sg1 * CAP + 16 + j];

    for (int r = 0; r <= N_REL; ++r) {
        if (r) __syncthreads();   // prior MFMA done reading meanT

        short8 sv0, sv1;
        if (r == N_REL) {  // root/self: copy own row
            sv0 = v0 ? *(const short8*)(xbf + (size_t)gn0 * 128 + j8)
                     : (short8){0, 0, 0, 0, 0, 0, 0, 0};
            sv1 = v1 ? *(const short8*)(xbf + (size_t)gn1 * 128 + j8)
                     : (short8){0, 0, 0, 0, 0, 0, 0, 0};
        } else {
            // prefetch next relation's cnt/ell (overlaps this r's gather)
            int nc0 = 0, nc1 = 0, nA0 = 0, nB0 = 0, nA1 = 0, nB1 = 0;
            if (r + 1 < N_REL) {
                size_t s0o = (size_t)(r + 1) * N_NODES;
                nc0 = v0 ? cnt[s0o + sg0] : 0;
                nc1 = v1 ? cnt[s0o + sg1] : 0;
                nA0 = ell[(s0o + sg0) * CAP + j];
                nB0 = ell[(s0o + sg0) * CAP + 16 + j];
                nA1 = ell[(s0o + sg1) * CAP + j];
                nB1 = ell[(s0o + sg1) * CAP + 16 + j];
            }

            int cA = c0 < CAP ? c0 : CAP;
            int cB = c1 < CAP ? c1 : CAP;
            int cm = cA > cB ? cA : cB;
            cm = (cm + 3) & ~3;

            f32x4 s00 = (f32x4){0.f, 0.f, 0.f, 0.f};
            f32x4 s01 = (f32x4){0.f, 0.f, 0.f, 0.f};
            f32x4 s10 = (f32x4){0.f, 0.f, 0.f, 0.f};
            f32x4 s11 = (f32x4){0.f, 0.f, 0.f, 0.f};

            for (int e = 0; e < cm; e += 4) {
                int b0 = (e < 16) ? pA0 : pB0;
                int b1 = (e < 16) ? pA1 : pB1;
                int i0[4], i1[4];
#pragma unroll
                for (int u = 0; u < 4; ++u) {
                    int sl = gb + ((e + u) & 15);
                    int t0 = __shfl(b0, sl, 64);
                    int t1 = __shfl(b1, sl, 64);
                    i0[u] = (e + u < cA) ? t0 : N_NODES;  // sentinel -> zero row
                    i1[u] = (e + u < cB) ? t1 : N_NODES;
                }
                short8 w0[4], w1[4];
#pragma unroll
                for (int u = 0; u < 4; ++u)
                    w0[u] = *(const short8*)(xbf + (size_t)i0[u] * 128 + j8);
#pragma unroll
                for (int u = 0; u < 4; ++u)
                    w1[u] = *(const short8*)(xbf + (size_t)i1[u] * 128 + j8);
#pragma unroll
                for (int u = 0; u < 4; ++u) {
                    uint4 w = __builtin_bit_cast(uint4, w0[u]);
                    s00.x += u2f(w.x << 16);
                    s00.y += u2f(w.x & 0xFFFF0000u);
                    s00.z += u2f(w.y << 16);
                    s00.w += u2f(w.y & 0xFFFF0000u);
                    s01.x += u2f(w.z << 16);
                    s01.y += u2f(w.z & 0xFFFF0000u);
                    s01.z += u2f(w.w << 16);
                    s01.w += u2f(w.w & 0xFFFF0000u);
                }
#pragma unroll
                for (int u = 0; u < 4; ++u) {
                    uint4 w = __builtin_bit_cast(uint4, w1[u]);
                    s10.x += u2f(w.x << 16);
                    s10.y += u2f(w.x & 0xFFFF0000u);
                    s10.z += u2f(w.y << 16);
                    s10.w += u2f(w.y & 0xFFFF0000u);
                    s11.x += u2f(w.z << 16);
                    s11.y += u2f(w.z & 0xFFFF0000u);
                    s11.z += u2f(w.w << 16);
                    s11.w += u2f(w.w & 0xFFFF0000u);
                }
            }
            float inv0 = 1.f / (float)(c0 > 1 ? c0 : 1);
            float inv1 = 1.f / (float)(c1 > 1 ? c1 : 1);
            s00 *= inv0; s01 *= inv0;
            s10 *= inv1; s11 *= inv1;
            sv0 = (short8){(short)f2bf(s00.x), (short)f2bf(s00.y),
                           (short)f2bf(s00.z), (short)f2bf(s00.w),
                           (short)f2bf(s01.x), (short)f2bf(s01.y),
                           (short)f2bf(s01.z), (short)f2bf(s01.w)};
            sv1 = (short8){(short)f2bf(s10.x), (short)f2bf(s10.y),
                           (short)f2bf(s10.z), (short)f2bf(s10.w),
                           (short)f2bf(s11.x), (short)f2bf(s11.y),
                           (short)f2bf(s11.z), (short)f2bf(s11.w)};
            // rotate prefetch registers
            c0 = nc0; c1 = nc1;
            pA0 = nA0; pB0 = nB0; pA1 = nA1; pB1 = nB1;
        }
        *(short8*)&meanT[g * LDK + j8]        = sv0;
        *(short8*)&meanT[(16 + g) * LDK + j8] = sv1;
        __syncthreads();

        // ---- MFMA: A from LDS, B straight from global (L2-resident Wt) ----
        const ushort* Wr = Wt + (size_t)r * OUTC * 128;
        short8 af[4];
        const int m = rt * 16 + lr;
#pragma unroll
        for (int ks = 0; ks < 4; ++ks)
            af[ks] = *(const short8*)&meanT[m * LDK + ks * 32 + kc];
#pragma unroll
        for (int t = 0; t < NTW; ++t) {
            const int n = (ch * NTW + t) * 16 + lr;
            f32x4 a = acc[t];
#pragma unroll
            for (int ks = 0; ks < 4; ++ks) {
                short8 bf = *(const short8*)(Wr + (size_t)n * 128 + ks * 32 + kc);
                a = __builtin_amdgcn_mfma_f32_16x16x32_bf16(af[ks], bf, a, 0, 0, 0);
            }
            acc[t] = a;
        }
    }

    // ---- epilogue ----
    const int rq = (lane >> 4) * 4;
#pragma unroll
    for (int t = 0; t < NTW; ++t) {
        int col  = (ch * NTW + t) * 16 + lr;
        float bv = bias[col];
#pragma unroll
        for (int q = 0; q < 4; ++q) {
            int node = nbase + rt * 16 + rq + q;
            if (node < N_NODES) {
                float v = acc[t][q] + bv;
                if (RELU) v = fmaxf(v, 0.f);
                if (BF16OUT)
                    ((ushort*)outp)[(size_t)node * OUTC + col] = f2bf(v);
                else
                    ((float*)outp)[(size_t)node * OUTC + col] = v;
            }
        }
    }
}

extern "C" void kernel_launch(void* const* d_in, const int* in_sizes, int n_in,
                              void* d_out, int out_size, void* d_ws, size_t ws_size,
                              hipStream_t stream) {
    const float* x        = (const float*)d_in[0];
    const int*   A        = (const int*)d_in[1];
    const int*   etype    = (const int*)d_in[2];
    const float* w1_basis = (const float*)d_in[3];
    const float* w1_comp  = (const float*)d_in[4];
    const float* w1_root  = (const float*)d_in[5];
    const float* w1_bias  = (const float*)d_in[6];
    const float* w2_basis = (const float*)d_in[7];
    const float* w2_comp  = (const float*)d_in[8];
    const float* w2_root  = (const float*)d_in[9];
    const float* w2_bias  = (const float*)d_in[10];
    float* out = (float*)d_out;

    char* ws = (char*)d_ws;
    ushort* Wt1  = (ushort*)(ws);                   // 294,912 B
    ushort* Wt2  = (ushort*)(ws + (512 << 10));     // 147,456 B
    int*    cnt  = (int*)(ws + (1 << 20));          // 1.6 MB
    ushort* x_bf = (ushort*)(ws + (3ull << 20));    // 12.8 MB ((N+1)*128)
    ushort* h_bf = (ushort*)(ws + (16ull << 20));   // 12.8 MB
    int*    ell  = (int*)(ws + (29ull << 20));      // 51.2 MB

    zero_i32_kernel<<<(N_REL * N_NODES + 255) / 256, 256, 0, stream>>>(
        cnt, N_REL * N_NODES);
    to_bf16_kernel<<<((N_NODES + 1) * 16 + 255) / 256, 256, 0, stream>>>(x, x_bf);
    zero_i32_kernel<<<1, 64, 0, stream>>>((int*)(h_bf + (size_t)N_NODES * 128), 64);
    compose_wt_kernel<<<(9 * 128 * 128 + 255) / 256, 256, 0, stream>>>(
        w1_basis, w1_comp, w1_root, Wt1, 128, 9 * 128 * 128);
    compose_wt_kernel<<<(9 * 64 * 128 + 255) / 256, 256, 0, stream>>>(
        w2_basis, w2_comp, w2_root, Wt2, 64, 9 * 64 * 128);
    build_ell_kernel<<<(N_EDGES + 255) / 256, 256, 0, stream>>>(A, etype, cnt, ell);

    int grid = (N_NODES + 31) / 32;  // 1563
    rgcn_layer_mfma<128, true, true><<<grid, 256, 0, stream>>>(
        x_bf, cnt, ell, Wt1, w1_bias, h_bf);
    rgcn_layer_mfma<64, false, false><<<grid, 256, 0, stream>>>(
        h_bf, cnt, ell, Wt2, w2_bias, out);
}

// Round 7
// 417.235 us; speedup vs baseline: 1.2229x; 1.2229x over previous
//
#include <hip/hip_runtime.h>

// RGCN 2-layer, basis decomposition, mean aggregation - MFMA, occupancy-optimized.
// N=50000, E=1.6M, R=8, feat 128->128->64.
//
// Round-6: round-4 structure (Wl in LDS, two-pass 4-deep gather) but W^T staged
// in 64-row chunks -> LDS 26.1 KB -> 6 blocks/CU (was 3): whole grid resident,
// 2x in-flight gather loads per CU.

#define N_NODES 50000
#define N_EDGES 1600000
#define N_REL   8
#define CAP     32

typedef __attribute__((ext_vector_type(8))) short short8;
typedef __attribute__((ext_vector_type(4))) float f32x4;

__device__ __forceinline__ ushort f2bf(float x) {
    unsigned u = __builtin_bit_cast(unsigned, x);
    u += 0x7FFFu + ((u >> 16) & 1u);   // RNE
    return (ushort)(u >> 16);
}
__device__ __forceinline__ float u2f(unsigned u) {
    return __builtin_bit_cast(float, u);
}

__global__ void zero_i32_kernel(int* __restrict__ p, int n) {
    int i = blockIdx.x * 256 + threadIdx.x;
    if (i < n) p[i] = 0;
}

// x (N,128) f32 -> xbf ((N+1),128) bf16, row N zeroed (gather sentinel).
__global__ void to_bf16_kernel(const float* __restrict__ in,
                               ushort* __restrict__ out) {
    int i = blockIdx.x * 256 + threadIdx.x;
    int total = (N_NODES + 1) * 16;
    if (i >= total) return;
    int base = i * 8;
    short8 v;
    if (base < N_NODES * 128) {
        f32x4 a = *(const f32x4*)(in + base);
        f32x4 b = *(const f32x4*)(in + base + 4);
        v = (short8){(short)f2bf(a.x), (short)f2bf(a.y), (short)f2bf(a.z),
                     (short)f2bf(a.w), (short)f2bf(b.x), (short)f2bf(b.y),
                     (short)f2bf(b.z), (short)f2bf(b.w)};
    } else {
        v = (short8){0, 0, 0, 0, 0, 0, 0, 0};
    }
    *(short8*)(out + base) = v;
}

// Wt[(r*outc + n)*128 + k] = bf16( sum_b comp[r,b]*basis[b,k,n] ), r==8 -> root
__global__ void compose_wt_kernel(const float* __restrict__ basis,
                                  const float* __restrict__ comp,
                                  const float* __restrict__ root,
                                  ushort* __restrict__ Wt,
                                  int outc, int total) {
    int i = blockIdx.x * 256 + threadIdx.x;
    if (i >= total) return;
    int per_r = outc << 7;
    int r = i / per_r;
    int rem = i - r * per_r;
    int n = rem >> 7;
    int k = rem & 127;
    float s;
    if (r == N_REL) {
        s = root[k * outc + n];
    } else {
        s = 0.f;
#pragma unroll
        for (int b = 0; b < 4; ++b)
            s += comp[r * 4 + b] * basis[(b * 128 + k) * outc + n];
    }
    Wt[i] = f2bf(s);
}

__global__ void build_ell_kernel(const int* __restrict__ A,
                                 const int* __restrict__ etype,
                                 int* __restrict__ cnt,
                                 int* __restrict__ ell) {
    int e = blockIdx.x * 256 + threadIdx.x;
    if (e >= N_EDGES) return;
    int s = A[e];
    int d = A[N_EDGES + e];
    int t = etype[e];
    int seg = t * N_NODES + d;
    int slot = atomicAdd(&cnt[seg], 1);
    if (slot < CAP) ell[(size_t)seg * CAP + slot] = s;
}

template <int OUTC, bool RELU, bool BF16OUT>
__global__ __launch_bounds__(256, 6)
void rgcn_layer_mfma(const ushort* __restrict__ xbf,  // (N+1,128) bf16
                     const int* __restrict__ cnt,     // (R*N,)
                     const int* __restrict__ ell,     // (R*N,CAP)
                     const ushort* __restrict__ Wt,   // (R+1,OUTC,128) bf16
                     const float* __restrict__ bias,  // (OUTC,)
                     void* __restrict__ outp) {       // (N,OUTC)
    constexpr int LDK = 136;        // padded k-stride (272 B rows)
    constexpr int TN  = 32;
    constexpr int NTW = OUTC / 32;  // accumulator tiles per wave (4 / 2)
    constexpr int NCH = OUTC / 64;  // 64-row W chunks (2 / 1)

    __shared__ ushort meanT[TN * LDK];   // 8.7 KB
    __shared__ ushort Wl[64 * LDK];      // 17.4 KB  -> total 26.1 KB, 6 blk/CU

    const int tid   = threadIdx.x;
    const int lane  = tid & 63;
    const int wave  = tid >> 6;
    const int nbase = blockIdx.x * TN;

    // gather mapping: 16 lanes per node, lane j owns features [8j,8j+8)
    const int g  = tid >> 4;
    const int j  = tid & 15;
    const int j8 = j * 8;
    const int gb = lane & 48;

    // MFMA mapping
    const int rt = wave & 1;          // 16-node row tile
    const int ch = wave >> 1;         // 32-col half within a 64-row W chunk
    const int lr = lane & 15;
    const int kc = (lane >> 4) * 8;

    f32x4 acc[NTW];
#pragma unroll
    for (int t = 0; t < NTW; ++t) acc[t] = (f32x4){0.f, 0.f, 0.f, 0.f};

    for (int r = 0; r <= N_REL; ++r) {
        if (r) __syncthreads();   // prior MFMA done reading meanT/Wl

        // ---- gather-mean 32 nodes into meanT (two passes, 4-deep) ----
#pragma unroll
        for (int p = 0; p < 2; ++p) {
            int a  = p * 16 + g;
            int gn = nbase + a;
            short8 sv = (short8){0, 0, 0, 0, 0, 0, 0, 0};
            if (gn < N_NODES) {
                if (r == N_REL) {
                    sv = *(const short8*)(xbf + (size_t)gn * 128 + j8);
                } else {
                    int seg = r * N_NODES + gn;
                    int c   = cnt[seg];
                    int cc  = c < CAP ? c : CAP;
                    const int* el = ell + (size_t)seg * CAP;
                    int pre0 = (j < cc) ? el[j] : N_NODES;
                    int pre1 = (16 + j < cc) ? el[16 + j] : N_NODES;
                    f32x4 s0 = (f32x4){0.f, 0.f, 0.f, 0.f};
                    f32x4 s1 = (f32x4){0.f, 0.f, 0.f, 0.f};
                    int ccr = (cc + 3) & ~3;
                    for (int e = 0; e < ccr; e += 4) {
                        int base = (e < 16) ? pre0 : pre1;
                        int i0 = __shfl(base, gb + ((e + 0) & 15), 64);
                        int i1 = __shfl(base, gb + ((e + 1) & 15), 64);
                        int i2 = __shfl(base, gb + ((e + 2) & 15), 64);
                        int i3 = __shfl(base, gb + ((e + 3) & 15), 64);
                        i0 = (e + 0 < cc) ? i0 : N_NODES;
                        i1 = (e + 1 < cc) ? i1 : N_NODES;
                        i2 = (e + 2 < cc) ? i2 : N_NODES;
                        i3 = (e + 3 < cc) ? i3 : N_NODES;
                        short8 v0 = *(const short8*)(xbf + (size_t)i0 * 128 + j8);
                        short8 v1 = *(const short8*)(xbf + (size_t)i1 * 128 + j8);
                        short8 v2 = *(const short8*)(xbf + (size_t)i2 * 128 + j8);
                        short8 v3 = *(const short8*)(xbf + (size_t)i3 * 128 + j8);
#pragma unroll
                        for (int u = 0; u < 4; ++u) {
                            short8 v = (u == 0) ? v0 : (u == 1) ? v1
                                     : (u == 2) ? v2 : v3;
                            uint4 w = __builtin_bit_cast(uint4, v);
                            s0.x += u2f(w.x << 16);
                            s0.y += u2f(w.x & 0xFFFF0000u);
                            s0.z += u2f(w.y << 16);
                            s0.w += u2f(w.y & 0xFFFF0000u);
                            s1.x += u2f(w.z << 16);
                            s1.y += u2f(w.z & 0xFFFF0000u);
                            s1.z += u2f(w.w << 16);
                            s1.w += u2f(w.w & 0xFFFF0000u);
                        }
                    }
                    float inv = 1.f / (float)(c > 1 ? c : 1);
                    s0 *= inv;
                    s1 *= inv;
                    sv = (short8){(short)f2bf(s0.x), (short)f2bf(s0.y),
                                  (short)f2bf(s0.z), (short)f2bf(s0.w),
                                  (short)f2bf(s1.x), (short)f2bf(s1.y),
                                  (short)f2bf(s1.z), (short)f2bf(s1.w)};
                }
            }
            *(short8*)&meanT[a * LDK + j8] = sv;
        }

        // ---- per 64-row W chunk: stage -> sync -> MFMA ----
        short8 af[4];
        const int m = rt * 16 + lr;
#pragma unroll
        for (int c = 0; c < NCH; ++c) {
            if (c) __syncthreads();   // prev chunk's MFMA done reading Wl
            {   // stage 64 rows of W_r^T (coalesced float4)
                const float4* src =
                    (const float4*)(Wt + ((size_t)r * OUTC + c * 64) * 128);
#pragma unroll
                for (int q = 0; q < 4; ++q) {
                    int idx = tid + q * 256;
                    int n   = idx >> 4;
                    int k8  = idx & 15;
                    *(float4*)&Wl[n * LDK + k8 * 8] = src[idx];
                }
            }
            __syncthreads();          // Wl (and on c==0: meanT) ready
            if (c == 0) {
#pragma unroll
                for (int ks = 0; ks < 4; ++ks)
                    af[ks] = *(const short8*)&meanT[m * LDK + ks * 32 + kc];
            }
#pragma unroll
            for (int tc = 0; tc < 2; ++tc) {
                const int t = c * 2 + tc;
                const int n = ch * 32 + tc * 16 + lr;   // row within chunk
                f32x4 a = acc[t];
#pragma unroll
                for (int ks = 0; ks < 4; ++ks) {
                    short8 bf = *(const short8*)&Wl[n * LDK + ks * 32 + kc];
                    a = __builtin_amdgcn_mfma_f32_16x16x32_bf16(af[ks], bf, a,
                                                                0, 0, 0);
                }
                acc[t] = a;
            }
        }
    }

    // ---- epilogue: bias (+relu) ----
    const int rq = (lane >> 4) * 4;
#pragma unroll
    for (int t = 0; t < NTW; ++t) {
        int col  = (t >> 1) * 64 + ch * 32 + (t & 1) * 16 + lr;
        float bv = bias[col];
#pragma unroll
        for (int q = 0; q < 4; ++q) {
            int node = nbase + rt * 16 + rq + q;
            if (node < N_NODES) {
                float v = acc[t][q] + bv;
                if (RELU) v = fmaxf(v, 0.f);
                if (BF16OUT)
                    ((ushort*)outp)[(size_t)node * OUTC + col] = f2bf(v);
                else
                    ((float*)outp)[(size_t)node * OUTC + col] = v;
            }
        }
    }
}

extern "C" void kernel_launch(void* const* d_in, const int* in_sizes, int n_in,
                              void* d_out, int out_size, void* d_ws, size_t ws_size,
                              hipStream_t stream) {
    const float* x        = (const float*)d_in[0];
    const int*   A        = (const int*)d_in[1];
    const int*   etype    = (const int*)d_in[2];
    const float* w1_basis = (const float*)d_in[3];
    const float* w1_comp  = (const float*)d_in[4];
    const float* w1_root  = (const float*)d_in[5];
    const float* w1_bias  = (const float*)d_in[6];
    const float* w2_basis = (const float*)d_in[7];
    const float* w2_comp  = (const float*)d_in[8];
    const float* w2_root  = (const float*)d_in[9];
    const float* w2_bias  = (const float*)d_in[10];
    float* out = (float*)d_out;

    char* ws = (char*)d_ws;
    ushort* Wt1  = (ushort*)(ws);                   // 294,912 B
    ushort* Wt2  = (ushort*)(ws + (512 << 10));     // 147,456 B
    int*    cnt  = (int*)(ws + (1 << 20));          // 1.6 MB
    ushort* x_bf = (ushort*)(ws + (3ull << 20));    // 12.8 MB ((N+1)*128)
    ushort* h_bf = (ushort*)(ws + (16ull << 20));   // 12.8 MB
    int*    ell  = (int*)(ws + (29ull << 20));      // 51.2 MB

    zero_i32_kernel<<<(N_REL * N_NODES + 255) / 256, 256, 0, stream>>>(
        cnt, N_REL * N_NODES);
    to_bf16_kernel<<<((N_NODES + 1) * 16 + 255) / 256, 256, 0, stream>>>(x, x_bf);
    zero_i32_kernel<<<1, 64, 0, stream>>>((int*)(h_bf + (size_t)N_NODES * 128), 64);
    compose_wt_kernel<<<(9 * 128 * 128 + 255) / 256, 256, 0, stream>>>(
        w1_basis, w1_comp, w1_root, Wt1, 128, 9 * 128 * 128);
    compose_wt_kernel<<<(9 * 64 * 128 + 255) / 256, 256, 0, stream>>>(
        w2_basis, w2_comp, w2_root, Wt2, 64, 9 * 64 * 128);
    build_ell_kernel<<<(N_EDGES + 255) / 256, 256, 0, stream>>>(A, etype, cnt, ell);

    int grid = (N_NODES + 31) / 32;  // 1563
    rgcn_layer_mfma<128, true, true><<<grid, 256, 0, stream>>>(
        x_bf, cnt, ell, Wt1, w1_bias, h_bf);
    rgcn_layer_mfma<64, false, false><<<grid, 256, 0, stream>>>(
        h_bf, cnt, ell, Wt2, w2_bias, out);
}

// Round 8
// 386.689 us; speedup vs baseline: 1.3195x; 1.0790x over previous
//
#include <hip/hip_runtime.h>

// RGCN 2-layer, basis decomposition, mean aggregation - MFMA, full-residency.
// N=50000, E=1.6M, R=8, feat 128->128->64.
//
// Round-8: LDS 17.4 KB (meanT + 32-row W chunk) + VGPR<=64 -> 8 blocks/CU =
// 2048 slots >= 1563-block grid: whole grid resident, no dispatch tail.
// u16 ELL (ids < 65536): 1 dword load covers 2 slots, 1 shfl serves 2 edges.

#define N_NODES 50000
#define N_EDGES 1600000
#define N_REL   8
#define CAP     32

typedef __attribute__((ext_vector_type(8))) short short8;
typedef __attribute__((ext_vector_type(4))) float f32x4;

__device__ __forceinline__ ushort f2bf(float x) {
    unsigned u = __builtin_bit_cast(unsigned, x);
    u += 0x7FFFu + ((u >> 16) & 1u);   // RNE
    return (ushort)(u >> 16);
}
__device__ __forceinline__ float u2f(unsigned u) {
    return __builtin_bit_cast(float, u);
}

__global__ void zero_i32_kernel(int* __restrict__ p, int n) {
    int i = blockIdx.x * 256 + threadIdx.x;
    if (i < n) p[i] = 0;
}

// x (N,128) f32 -> xbf ((N+1),128) bf16, row N zeroed (gather sentinel).
__global__ void to_bf16_kernel(const float* __restrict__ in,
                               ushort* __restrict__ out) {
    int i = blockIdx.x * 256 + threadIdx.x;
    int total = (N_NODES + 1) * 16;
    if (i >= total) return;
    int base = i * 8;
    short8 v;
    if (base < N_NODES * 128) {
        f32x4 a = *(const f32x4*)(in + base);
        f32x4 b = *(const f32x4*)(in + base + 4);
        v = (short8){(short)f2bf(a.x), (short)f2bf(a.y), (short)f2bf(a.z),
                     (short)f2bf(a.w), (short)f2bf(b.x), (short)f2bf(b.y),
                     (short)f2bf(b.z), (short)f2bf(b.w)};
    } else {
        v = (short8){0, 0, 0, 0, 0, 0, 0, 0};
    }
    *(short8*)(out + base) = v;
}

// Wt[(r*outc + n)*128 + k] = bf16( sum_b comp[r,b]*basis[b,k,n] ), r==8 -> root
__global__ void compose_wt_kernel(const float* __restrict__ basis,
                                  const float* __restrict__ comp,
                                  const float* __restrict__ root,
                                  ushort* __restrict__ Wt,
                                  int outc, int total) {
    int i = blockIdx.x * 256 + threadIdx.x;
    if (i >= total) return;
    int per_r = outc << 7;
    int r = i / per_r;
    int rem = i - r * per_r;
    int n = rem >> 7;
    int k = rem & 127;
    float s;
    if (r == N_REL) {
        s = root[k * outc + n];
    } else {
        s = 0.f;
#pragma unroll
        for (int b = 0; b < 4; ++b)
            s += comp[r * 4 + b] * basis[(b * 128 + k) * outc + n];
    }
    Wt[i] = f2bf(s);
}

__global__ void build_ell_kernel(const int* __restrict__ A,
                                 const int* __restrict__ etype,
                                 int* __restrict__ cnt,
                                 ushort* __restrict__ ell) {   // (R*N, CAP) u16
    int e = blockIdx.x * 256 + threadIdx.x;
    if (e >= N_EDGES) return;
    int s = A[e];
    int d = A[N_EDGES + e];
    int t = etype[e];
    int seg = t * N_NODES + d;
    int slot = atomicAdd(&cnt[seg], 1);
    if (slot < CAP) ell[(size_t)seg * CAP + slot] = (ushort)s;
}

template <int OUTC, bool RELU, bool BF16OUT>
__global__ __launch_bounds__(256, 8)
void rgcn_layer_mfma(const ushort* __restrict__ xbf,  // (N+1,128) bf16
                     const int* __restrict__ cnt,     // (R*N,)
                     const ushort* __restrict__ ell,  // (R*N,CAP) u16
                     const ushort* __restrict__ Wt,   // (R+1,OUTC,128) bf16
                     const float* __restrict__ bias,  // (OUTC,)
                     void* __restrict__ outp) {       // (N,OUTC)
    constexpr int LDK = 136;        // padded k-stride (272 B rows)
    constexpr int TN  = 32;
    constexpr int NCH = OUTC / 32;  // 32-row W chunks (4 / 2) = acc tiles/wave

    __shared__ ushort meanT[TN * LDK];   // 8.7 KB
    __shared__ ushort Wl[32 * LDK];      // 8.7 KB -> total 17.4 KB, 8 blk/CU

    const int tid   = threadIdx.x;
    const int lane  = tid & 63;
    const int wave  = tid >> 6;
    const int nbase = blockIdx.x * TN;

    // gather mapping: 16 lanes per node, lane j owns features [8j,8j+8)
    const int g  = tid >> 4;
    const int j  = tid & 15;
    const int j8 = j * 8;
    const int gb = lane & 48;

    // MFMA mapping
    const int rt = wave & 1;          // 16-node row tile
    const int ch = wave >> 1;         // 16-col half within a 32-col W chunk
    const int lr = lane & 15;
    const int kc = (lane >> 4) * 8;

    f32x4 acc[NCH];
#pragma unroll
    for (int t = 0; t < NCH; ++t) acc[t] = (f32x4){0.f, 0.f, 0.f, 0.f};

    for (int r = 0; r <= N_REL; ++r) {
        // ---- gather-mean 32 nodes into meanT (two passes, 4-deep) ----
        // (overlaps the tail of r-1's last MFMA chunk; doesn't touch Wl)
#pragma unroll
        for (int p = 0; p < 2; ++p) {
            int a  = p * 16 + g;
            int gn = nbase + a;
            short8 sv = (short8){0, 0, 0, 0, 0, 0, 0, 0};
            if (gn < N_NODES) {
                if (r == N_REL) {
                    sv = *(const short8*)(xbf + (size_t)gn * 128 + j8);
                } else {
                    int seg = r * N_NODES + gn;
                    int c   = cnt[seg];
                    int cc  = c < CAP ? c : CAP;
                    // lane j holds slots {2j, 2j+1} of this node's list
                    uint pre = *(const uint*)(ell + (size_t)seg * CAP + 2 * j);
                    f32x4 s0 = (f32x4){0.f, 0.f, 0.f, 0.f};
                    f32x4 s1 = (f32x4){0.f, 0.f, 0.f, 0.f};
                    int ccr = (cc + 3) & ~3;
                    for (int e = 0; e < ccr; e += 4) {
                        uint ua = __shfl(pre, gb + (e >> 1), 64);
                        uint ub = __shfl(pre, gb + (e >> 1) + 1, 64);
                        int i0 = (e + 0 < cc) ? (int)(ua & 0xFFFFu) : N_NODES;
                        int i1 = (e + 1 < cc) ? (int)(ua >> 16)     : N_NODES;
                        int i2 = (e + 2 < cc) ? (int)(ub & 0xFFFFu) : N_NODES;
                        int i3 = (e + 3 < cc) ? (int)(ub >> 16)     : N_NODES;
                        short8 v0 = *(const short8*)(xbf + (size_t)i0 * 128 + j8);
                        short8 v1 = *(const short8*)(xbf + (size_t)i1 * 128 + j8);
                        short8 v2 = *(const short8*)(xbf + (size_t)i2 * 128 + j8);
                        short8 v3 = *(const short8*)(xbf + (size_t)i3 * 128 + j8);
#pragma unroll
                        for (int u = 0; u < 4; ++u) {
                            short8 v = (u == 0) ? v0 : (u == 1) ? v1
                                     : (u == 2) ? v2 : v3;
                            uint4 w = __builtin_bit_cast(uint4, v);
                            s0.x += u2f(w.x << 16);
                            s0.y += u2f(w.x & 0xFFFF0000u);
                            s0.z += u2f(w.y << 16);
                            s0.w += u2f(w.y & 0xFFFF0000u);
                            s1.x += u2f(w.z << 16);
                            s1.y += u2f(w.z & 0xFFFF0000u);
                            s1.z += u2f(w.w << 16);
                            s1.w += u2f(w.w & 0xFFFF0000u);
                        }
                    }
                    float inv = 1.f / (float)(c > 1 ? c : 1);
                    s0 *= inv;
                    s1 *= inv;
                    sv = (short8){(short)f2bf(s0.x), (short)f2bf(s0.y),
                                  (short)f2bf(s0.z), (short)f2bf(s0.w),
                                  (short)f2bf(s1.x), (short)f2bf(s1.y),
                                  (short)f2bf(s1.z), (short)f2bf(s1.w)};
                }
            }
            *(short8*)&meanT[a * LDK + j8] = sv;
        }
        __syncthreads();   // meanT ready; prev r's MFMA done -> Wl writable

        // A-fragments for this r (meanT free for next r after this)
        short8 af[4];
        const int m = rt * 16 + lr;
#pragma unroll
        for (int ks = 0; ks < 4; ++ks)
            af[ks] = *(const short8*)&meanT[m * LDK + ks * 32 + kc];

        // ---- per 32-row W chunk: stage -> sync -> MFMA (-> sync) ----
#pragma unroll
        for (int c = 0; c < NCH; ++c) {
            {   // stage 32 rows of W_r^T (coalesced float4, 2 per thread)
                const float4* src =
                    (const float4*)(Wt + ((size_t)r * OUTC + c * 32) * 128);
#pragma unroll
                for (int q = 0; q < 2; ++q) {
                    int idx = tid + q * 256;
                    int n   = idx >> 4;
                    int k8  = idx & 15;
                    *(float4*)&Wl[n * LDK + k8 * 8] = src[idx];
                }
            }
            __syncthreads();          // Wl ready
            const int n = ch * 16 + lr;     // row within chunk
            f32x4 a = acc[c];
#pragma unroll
            for (int ks = 0; ks < 4; ++ks) {
                short8 bf = *(const short8*)&Wl[n * LDK + ks * 32 + kc];
                a = __builtin_amdgcn_mfma_f32_16x16x32_bf16(af[ks], bf, a,
                                                            0, 0, 0);
            }
            acc[c] = a;
            if (c + 1 < NCH) __syncthreads();  // MFMA done reading Wl
            // last chunk: next r's gather doesn't touch Wl; its __syncthreads
            // (after meanT write) orders the next stage.
        }
    }

    // ---- epilogue: bias (+relu) ----
    const int rq = (lane >> 4) * 4;
#pragma unroll
    for (int t = 0; t < NCH; ++t) {
        int col  = t * 32 + ch * 16 + lr;
        float bv = bias[col];
#pragma unroll
        for (int q = 0; q < 4; ++q) {
            int node = nbase + rt * 16 + rq + q;
            if (node < N_NODES) {
                float v = acc[t][q] + bv;
                if (RELU) v = fmaxf(v, 0.f);
                if (BF16OUT)
                    ((ushort*)outp)[(size_t)node * OUTC + col] = f2bf(v);
                else
                    ((float*)outp)[(size_t)node * OUTC + col] = v;
            }
        }
    }
}

extern "C" void kernel_launch(void* const* d_in, const int* in_sizes, int n_in,
                              void* d_out, int out_size, void* d_ws, size_t ws_size,
                              hipStream_t stream) {
    const float* x        = (const float*)d_in[0];
    const int*   A        = (const int*)d_in[1];
    const int*   etype    = (const int*)d_in[2];
    const float* w1_basis = (const float*)d_in[3];
    const float* w1_comp  = (const float*)d_in[4];
    const float* w1_root  = (const float*)d_in[5];
    const float* w1_bias  = (const float*)d_in[6];
    const float* w2_basis = (const float*)d_in[7];
    const float* w2_comp  = (const float*)d_in[8];
    const float* w2_root  = (const float*)d_in[9];
    const float* w2_bias  = (const float*)d_in[10];
    float* out = (float*)d_out;

    char* ws = (char*)d_ws;
    ushort* Wt1  = (ushort*)(ws);                   // 294,912 B
    ushort* Wt2  = (ushort*)(ws + (512 << 10));     // 147,456 B
    int*    cnt  = (int*)(ws + (1 << 20));          // 1.6 MB
    ushort* x_bf = (ushort*)(ws + (3ull << 20));    // 12.8 MB ((N+1)*128)
    ushort* h_bf = (ushort*)(ws + (16ull << 20));   // 12.8 MB
    ushort* ell  = (ushort*)(ws + (29ull << 20));   // 25.6 MB u16

    zero_i32_kernel<<<(N_REL * N_NODES + 255) / 256, 256, 0, stream>>>(
        cnt, N_REL * N_NODES);
    to_bf16_kernel<<<((N_NODES + 1) * 16 + 255) / 256, 256, 0, stream>>>(x, x_bf);
    zero_i32_kernel<<<1, 64, 0, stream>>>((int*)(h_bf + (size_t)N_NODES * 128), 64);
    compose_wt_kernel<<<(9 * 128 * 128 + 255) / 256, 256, 0, stream>>>(
        w1_basis, w1_comp, w1_root, Wt1, 128, 9 * 128 * 128);
    compose_wt_kernel<<<(9 * 64 * 128 + 255) / 256, 256, 0, stream>>>(
        w2_basis, w2_comp, w2_root, Wt2, 64, 9 * 64 * 128);
    build_ell_kernel<<<(N_EDGES + 255) / 256, 256, 0, stream>>>(A, etype, cnt, ell);

    int grid = (N_NODES + 31) / 32;  // 1563
    rgcn_layer_mfma<128, true, true><<<grid, 256, 0, stream>>>(
        x_bf, cnt, ell, Wt1, w1_bias, h_bf);
    rgcn_layer_mfma<64, false, false><<<grid, 256, 0, stream>>>(
        h_bf, cnt, ell, Wt2, w2_bias, out);
}